// Round 1
// baseline (2979.288 us; speedup 1.0000x reference)
//
#include <hip/hip_runtime.h>

#define NN 50000
#define NE 800000
#define ND 64
#define ED 32
#define HID 64
#define NL 2
#define IN_MSG 96   // ND + ED
#define IN_UPD 128  // ND + HID

// ---------------------------------------------------------------------------
// Kernel 1: per-edge message MLP (2 small Linear-ReLU-Linear nets, summed),
// then atomic scatter-add into agg[dst] and deg[dst].
// One thread = one edge. Weights are wave-uniform -> s_load + SGPR-operand
// v_fma. All register arrays are compile-time indexed; the runtime-k reads
// of the hidden activations go through a conflict-free [k][tid] LDS stash.
// ---------------------------------------------------------------------------
__global__ __launch_bounds__(128, 2)
void edge_msg_kernel(const float* __restrict__ nf,
                     const float* __restrict__ ef,
                     const float* __restrict__ w1,
                     const float* __restrict__ b1,
                     const float* __restrict__ w2,
                     const float* __restrict__ b2,
                     const int* __restrict__ src,
                     const int* __restrict__ dst,
                     float* __restrict__ agg,
                     float* __restrict__ deg)
{
    __shared__ float hbuf[HID][128];  // 32 KiB; column tid is thread-private
    const int e = blockIdx.x * 128 + threadIdx.x;
    if (e >= NE) return;
    const int tid = threadIdx.x;
    const int s = src[e];
    const float4* nf4 = reinterpret_cast<const float4*>(nf + (size_t)s * ND);
    const float4* ef4 = reinterpret_cast<const float4*>(ef + (size_t)e * ED);

    float msg[HID];
    #pragma unroll
    for (int j = 0; j < HID; ++j) msg[j] = b2[j] + b2[HID + j];

    #pragma unroll 1
    for (int l = 0; l < NL; ++l) {
        const float* W1 = w1 + (size_t)l * IN_MSG * HID;
        const float* B1 = b1 + (size_t)l * HID;
        const float* W2 = w2 + (size_t)l * HID * HID;

        float h[HID];
        #pragma unroll
        for (int j = 0; j < HID; ++j) h[j] = B1[j];

        // combined[k] for k in [0,64): gathered source-node features
        #pragma unroll 1
        for (int kc = 0; kc < ND; kc += 8) {
            const float4 va = nf4[(kc >> 2) + 0];
            const float4 vb = nf4[(kc >> 2) + 1];
            const float c[8] = {va.x, va.y, va.z, va.w, vb.x, vb.y, vb.z, vb.w};
            #pragma unroll
            for (int i = 0; i < 8; ++i) {
                const float* row = W1 + (size_t)(kc + i) * HID;
                #pragma unroll
                for (int j = 0; j < HID; ++j) h[j] = fmaf(c[i], row[j], h[j]);
            }
        }
        // combined[k] for k in [64,96): edge features
        #pragma unroll 1
        for (int kc = 0; kc < ED; kc += 8) {
            const float4 va = ef4[(kc >> 2) + 0];
            const float4 vb = ef4[(kc >> 2) + 1];
            const float c[8] = {va.x, va.y, va.z, va.w, vb.x, vb.y, vb.z, vb.w};
            #pragma unroll
            for (int i = 0; i < 8; ++i) {
                const float* row = W1 + (size_t)(ND + kc + i) * HID;
                #pragma unroll
                for (int j = 0; j < HID; ++j) h[j] = fmaf(c[i], row[j], h[j]);
            }
        }

        // ReLU, stash to LDS so the second linear can index k at runtime
        #pragma unroll
        for (int j = 0; j < HID; ++j) hbuf[j][tid] = fmaxf(h[j], 0.0f);

        // second linear: msg += relu(h) @ W2
        #pragma unroll 1
        for (int kc = 0; kc < HID; kc += 8) {
            float c[8];
            #pragma unroll
            for (int i = 0; i < 8; ++i) c[i] = hbuf[kc + i][tid];
            #pragma unroll
            for (int i = 0; i < 8; ++i) {
                const float* row = W2 + (size_t)(kc + i) * HID;
                #pragma unroll
                for (int j = 0; j < HID; ++j) msg[j] = fmaf(c[i], row[j], msg[j]);
            }
        }
    }

    const int d = dst[e];
    float* arow = agg + (size_t)d * HID;
    #pragma unroll
    for (int j = 0; j < HID; ++j) atomicAdd(arow + j, msg[j]);
    atomicAdd(deg + d, 1.0f);
}

// ---------------------------------------------------------------------------
// Kernel 2: per-node update MLP on concat(node_features, agg/deg).
// One thread = one node; same SGPR-weight / LDS-stash structure.
// ---------------------------------------------------------------------------
__global__ __launch_bounds__(128, 2)
void node_update_kernel(const float* __restrict__ nf,
                        const float* __restrict__ agg,
                        const float* __restrict__ deg,
                        const float* __restrict__ uw1,
                        const float* __restrict__ ub1,
                        const float* __restrict__ uw2,
                        const float* __restrict__ ub2,
                        float* __restrict__ out)
{
    __shared__ float hbuf[HID][128];
    const int n = blockIdx.x * 128 + threadIdx.x;
    if (n >= NN) return;
    const int tid = threadIdx.x;
    const float invd = 1.0f / (deg[n] + 1e-8f);
    const float4* nf4 = reinterpret_cast<const float4*>(nf + (size_t)n * ND);
    const float4* ag4 = reinterpret_cast<const float4*>(agg + (size_t)n * HID);

    float h[HID];
    #pragma unroll
    for (int j = 0; j < HID; ++j) h[j] = ub1[j];

    // comb2[k] for k in [0,64): node features
    #pragma unroll 1
    for (int kc = 0; kc < ND; kc += 8) {
        const float4 va = nf4[(kc >> 2) + 0];
        const float4 vb = nf4[(kc >> 2) + 1];
        const float c[8] = {va.x, va.y, va.z, va.w, vb.x, vb.y, vb.z, vb.w};
        #pragma unroll
        for (int i = 0; i < 8; ++i) {
            const float* row = uw1 + (size_t)(kc + i) * HID;
            #pragma unroll
            for (int j = 0; j < HID; ++j) h[j] = fmaf(c[i], row[j], h[j]);
        }
    }
    // comb2[k] for k in [64,128): normalized aggregate
    #pragma unroll 1
    for (int kc = 0; kc < HID; kc += 8) {
        const float4 va = ag4[(kc >> 2) + 0];
        const float4 vb = ag4[(kc >> 2) + 1];
        const float c[8] = {va.x * invd, va.y * invd, va.z * invd, va.w * invd,
                            vb.x * invd, vb.y * invd, vb.z * invd, vb.w * invd};
        #pragma unroll
        for (int i = 0; i < 8; ++i) {
            const float* row = uw1 + (size_t)(ND + kc + i) * HID;
            #pragma unroll
            for (int j = 0; j < HID; ++j) h[j] = fmaf(c[i], row[j], h[j]);
        }
    }

    #pragma unroll
    for (int j = 0; j < HID; ++j) hbuf[j][tid] = fmaxf(h[j], 0.0f);

    float o[ND];
    #pragma unroll
    for (int j = 0; j < ND; ++j) o[j] = ub2[j];

    #pragma unroll 1
    for (int kc = 0; kc < HID; kc += 8) {
        float c[8];
        #pragma unroll
        for (int i = 0; i < 8; ++i) c[i] = hbuf[kc + i][tid];
        #pragma unroll
        for (int i = 0; i < 8; ++i) {
            const float* row = uw2 + (size_t)(kc + i) * ND;
            #pragma unroll
            for (int j = 0; j < ND; ++j) o[j] = fmaf(c[i], row[j], o[j]);
        }
    }

    float4* o4 = reinterpret_cast<float4*>(out + (size_t)n * ND);
    #pragma unroll
    for (int i = 0; i < ND / 4; ++i) {
        o4[i] = make_float4(o[4 * i + 0], o[4 * i + 1], o[4 * i + 2], o[4 * i + 3]);
    }
}

extern "C" void kernel_launch(void* const* d_in, const int* in_sizes, int n_in,
                              void* d_out, int out_size, void* d_ws, size_t ws_size,
                              hipStream_t stream)
{
    const float* nf  = (const float*)d_in[0];
    const float* ef  = (const float*)d_in[1];
    const float* w1  = (const float*)d_in[2];
    const float* b1  = (const float*)d_in[3];
    const float* w2  = (const float*)d_in[4];
    const float* b2  = (const float*)d_in[5];
    const float* uw1 = (const float*)d_in[6];
    const float* ub1 = (const float*)d_in[7];
    const float* uw2 = (const float*)d_in[8];
    const float* ub2 = (const float*)d_in[9];
    const int*   src = (const int*)d_in[10];
    const int*   dst = (const int*)d_in[11];
    float* out = (float*)d_out;

    float* agg = (float*)d_ws;                    // [NN][HID]
    float* deg = agg + (size_t)NN * HID;          // [NN]
    hipMemsetAsync(d_ws, 0, ((size_t)NN * HID + NN) * sizeof(float), stream);

    edge_msg_kernel<<<NE / 128, 128, 0, stream>>>(nf, ef, w1, b1, w2, b2,
                                                  src, dst, agg, deg);
    node_update_kernel<<<(NN + 127) / 128, 128, 0, stream>>>(nf, agg, deg,
                                                             uw1, ub1, uw2, ub2, out);
}

// Round 2
// 879.333 us; speedup vs baseline: 3.3881x; 3.3881x over previous
//
#include <hip/hip_runtime.h>

#define NN 50000
#define NE 800000
#define ND 64
#define ED 32
#define HID 64
#define NL 2
#define IN_MSG 96   // ND + ED
#define IN_UPD 128  // ND + HID
#define TILE 256

// ---------------------------------------------------------------------------
// Kernel 1: per-edge message MLP. Weights staged in LDS per layer (uniform
// broadcast ds_reads), h/msg fully register-resident (all compile-time
// indexed), scatter via per-wave LDS transpose -> coalesced row atomics.
// ---------------------------------------------------------------------------
__global__ __launch_bounds__(256, 3)
void edge_msg_kernel(const float* __restrict__ nf,
                     const float* __restrict__ ef,
                     const float* __restrict__ w1,
                     const float* __restrict__ b1,
                     const float* __restrict__ w2,
                     const float* __restrict__ b2,
                     const int* __restrict__ src,
                     const int* __restrict__ dst,
                     float* __restrict__ agg,
                     float* __restrict__ deg)
{
    __shared__ union SM {
        struct { float W1[IN_MSG * HID]; float W2[HID * HID]; } w;  // 40 KB
        float scat[2][64][65];                                      // 33.3 KB
    } sm;

    const int tid  = threadIdx.x;
    const int wave = tid >> 6;
    const int lane = tid & 63;
    const int e = blockIdx.x * TILE + tid;          // grid exact: 3125*256
    const int s = src[e];
    const float4* nf4 = reinterpret_cast<const float4*>(nf + (size_t)s * ND);
    const float4* ef4 = reinterpret_cast<const float4*>(ef + (size_t)e * ED);

    float msg[HID];
    #pragma unroll
    for (int j = 0; j < HID; ++j) msg[j] = b2[j] + b2[HID + j];

    float h[HID];

    #pragma unroll 1
    for (int l = 0; l < NL; ++l) {
        __syncthreads();   // protect LDS reuse (weights of prev layer / union)
        {   // cooperative stage of this layer's weights
            const float4* gW1 = reinterpret_cast<const float4*>(w1 + (size_t)l * IN_MSG * HID);
            float4* sW1 = reinterpret_cast<float4*>(sm.w.W1);
            #pragma unroll
            for (int i = 0; i < 6; ++i) sW1[tid + 256 * i] = gW1[tid + 256 * i];
            const float4* gW2 = reinterpret_cast<const float4*>(w2 + (size_t)l * HID * HID);
            float4* sW2 = reinterpret_cast<float4*>(sm.w.W2);
            #pragma unroll
            for (int i = 0; i < 4; ++i) sW2[tid + 256 * i] = gW2[tid + 256 * i];
        }
        __syncthreads();

        const float* B1 = b1 + l * HID;
        #pragma unroll
        for (int j = 0; j < HID; ++j) h[j] = B1[j];

        // --- GEMM1a: k in [0,64) gathered node features ---
        #pragma unroll 1
        for (int kc = 0; kc < ND; kc += 8) {
            const float4 va = nf4[(kc >> 2) + 0];
            const float4 vb = nf4[(kc >> 2) + 1];
            const float c[8] = {va.x, va.y, va.z, va.w, vb.x, vb.y, vb.z, vb.w};
            #pragma unroll
            for (int i = 0; i < 8; ++i) {
                const float* row = sm.w.W1 + (kc + i) * HID;
                #pragma unroll
                for (int jq = 0; jq < 16; ++jq) {
                    const float4 wv = *reinterpret_cast<const float4*>(row + jq * 4);
                    h[jq * 4 + 0] = fmaf(c[i], wv.x, h[jq * 4 + 0]);
                    h[jq * 4 + 1] = fmaf(c[i], wv.y, h[jq * 4 + 1]);
                    h[jq * 4 + 2] = fmaf(c[i], wv.z, h[jq * 4 + 2]);
                    h[jq * 4 + 3] = fmaf(c[i], wv.w, h[jq * 4 + 3]);
                }
            }
        }
        // --- GEMM1b: k in [64,96) edge features ---
        #pragma unroll 1
        for (int kc = 0; kc < ED; kc += 8) {
            const float4 va = ef4[(kc >> 2) + 0];
            const float4 vb = ef4[(kc >> 2) + 1];
            const float c[8] = {va.x, va.y, va.z, va.w, vb.x, vb.y, vb.z, vb.w};
            #pragma unroll
            for (int i = 0; i < 8; ++i) {
                const float* row = sm.w.W1 + (ND + kc + i) * HID;
                #pragma unroll
                for (int jq = 0; jq < 16; ++jq) {
                    const float4 wv = *reinterpret_cast<const float4*>(row + jq * 4);
                    h[jq * 4 + 0] = fmaf(c[i], wv.x, h[jq * 4 + 0]);
                    h[jq * 4 + 1] = fmaf(c[i], wv.y, h[jq * 4 + 1]);
                    h[jq * 4 + 2] = fmaf(c[i], wv.z, h[jq * 4 + 2]);
                    h[jq * 4 + 3] = fmaf(c[i], wv.w, h[jq * 4 + 3]);
                }
            }
        }
        // ReLU
        #pragma unroll
        for (int j = 0; j < HID; ++j) h[j] = fmaxf(h[j], 0.0f);

        // --- GEMM2: msg += relu(h) @ W2, fully unrolled (compile-time h[k]) ---
        #pragma unroll
        for (int k = 0; k < HID; ++k) {
            const float hv = h[k];
            const float* row = sm.w.W2 + k * HID;
            #pragma unroll
            for (int jq = 0; jq < 16; ++jq) {
                const float4 wv = *reinterpret_cast<const float4*>(row + jq * 4);
                msg[jq * 4 + 0] = fmaf(hv, wv.x, msg[jq * 4 + 0]);
                msg[jq * 4 + 1] = fmaf(hv, wv.y, msg[jq * 4 + 1]);
                msg[jq * 4 + 2] = fmaf(hv, wv.z, msg[jq * 4 + 2]);
                msg[jq * 4 + 3] = fmaf(hv, wv.w, msg[jq * 4 + 3]);
            }
        }
    }

    // ------- coalesced scatter: LDS transpose, one wave-atomic per edge row -
    const int blockBase = blockIdx.x * TILE;
    #pragma unroll 1
    for (int pass = 0; pass < 2; ++pass) {
        __syncthreads();                    // LDS region free (union w/ weights)
        if ((tid >> 7) == pass) {           // waves {0,1} then {2,3} stage tiles
            const int t = wave & 1;
            #pragma unroll
            for (int j = 0; j < HID; ++j) sm.scat[t][lane][j] = msg[j];
        }
        __syncthreads();
        // flush 128 edge rows; each wave takes 32 rows; 64-lane coalesced atomic
        #pragma unroll 4
        for (int rr = 0; rr < 32; ++rr) {
            const int r = (wave << 5) + rr;                 // 0..127
            const int eidx = blockBase + (pass << 7) + r;
            const int d = dst[eidx];
            const float v = sm.scat[r >> 6][r & 63][lane];
            atomicAdd(&agg[(size_t)d * HID + lane], v);
            if (lane == 0) atomicAdd(&deg[d], 1.0f);
        }
    }
}

// ---------------------------------------------------------------------------
// Kernel 2: per-node update MLP, same LDS-weight structure.
// ---------------------------------------------------------------------------
__global__ __launch_bounds__(256, 3)
void node_update_kernel(const float* __restrict__ nf,
                        const float* __restrict__ agg,
                        const float* __restrict__ deg,
                        const float* __restrict__ uw1,
                        const float* __restrict__ ub1,
                        const float* __restrict__ uw2,
                        const float* __restrict__ ub2,
                        float* __restrict__ out)
{
    __shared__ float sW1[IN_UPD * HID];   // 32 KB
    __shared__ float sW2[HID * ND];       // 16 KB

    const int tid = threadIdx.x;
    {   // stage
        const float4* g1 = reinterpret_cast<const float4*>(uw1);
        float4* s1 = reinterpret_cast<float4*>(sW1);
        #pragma unroll
        for (int i = 0; i < 8; ++i) s1[tid + 256 * i] = g1[tid + 256 * i];
        const float4* g2 = reinterpret_cast<const float4*>(uw2);
        float4* s2 = reinterpret_cast<float4*>(sW2);
        #pragma unroll
        for (int i = 0; i < 4; ++i) s2[tid + 256 * i] = g2[tid + 256 * i];
    }
    __syncthreads();

    const int n = blockIdx.x * 256 + tid;
    const bool valid = (n < NN);
    const int nc = valid ? n : (NN - 1);

    const float invd = 1.0f / (deg[nc] + 1e-8f);
    const float4* nf4 = reinterpret_cast<const float4*>(nf + (size_t)nc * ND);
    const float4* ag4 = reinterpret_cast<const float4*>(agg + (size_t)nc * HID);

    float h[HID];
    #pragma unroll
    for (int j = 0; j < HID; ++j) h[j] = ub1[j];

    #pragma unroll 1
    for (int kc = 0; kc < ND; kc += 8) {
        const float4 va = nf4[(kc >> 2) + 0];
        const float4 vb = nf4[(kc >> 2) + 1];
        const float c[8] = {va.x, va.y, va.z, va.w, vb.x, vb.y, vb.z, vb.w};
        #pragma unroll
        for (int i = 0; i < 8; ++i) {
            const float* row = sW1 + (kc + i) * HID;
            #pragma unroll
            for (int jq = 0; jq < 16; ++jq) {
                const float4 wv = *reinterpret_cast<const float4*>(row + jq * 4);
                h[jq * 4 + 0] = fmaf(c[i], wv.x, h[jq * 4 + 0]);
                h[jq * 4 + 1] = fmaf(c[i], wv.y, h[jq * 4 + 1]);
                h[jq * 4 + 2] = fmaf(c[i], wv.z, h[jq * 4 + 2]);
                h[jq * 4 + 3] = fmaf(c[i], wv.w, h[jq * 4 + 3]);
            }
        }
    }
    #pragma unroll 1
    for (int kc = 0; kc < HID; kc += 8) {
        const float4 va = ag4[(kc >> 2) + 0];
        const float4 vb = ag4[(kc >> 2) + 1];
        const float c[8] = {va.x * invd, va.y * invd, va.z * invd, va.w * invd,
                            vb.x * invd, vb.y * invd, vb.z * invd, vb.w * invd};
        #pragma unroll
        for (int i = 0; i < 8; ++i) {
            const float* row = sW1 + (ND + kc + i) * HID;
            #pragma unroll
            for (int jq = 0; jq < 16; ++jq) {
                const float4 wv = *reinterpret_cast<const float4*>(row + jq * 4);
                h[jq * 4 + 0] = fmaf(c[i], wv.x, h[jq * 4 + 0]);
                h[jq * 4 + 1] = fmaf(c[i], wv.y, h[jq * 4 + 1]);
                h[jq * 4 + 2] = fmaf(c[i], wv.z, h[jq * 4 + 2]);
                h[jq * 4 + 3] = fmaf(c[i], wv.w, h[jq * 4 + 3]);
            }
        }
    }
    #pragma unroll
    for (int j = 0; j < HID; ++j) h[j] = fmaxf(h[j], 0.0f);

    float o[ND];
    #pragma unroll
    for (int j = 0; j < ND; ++j) o[j] = ub2[j];

    #pragma unroll
    for (int k = 0; k < HID; ++k) {
        const float hv = h[k];
        const float* row = sW2 + k * ND;
        #pragma unroll
        for (int jq = 0; jq < 16; ++jq) {
            const float4 wv = *reinterpret_cast<const float4*>(row + jq * 4);
            o[jq * 4 + 0] = fmaf(hv, wv.x, o[jq * 4 + 0]);
            o[jq * 4 + 1] = fmaf(hv, wv.y, o[jq * 4 + 1]);
            o[jq * 4 + 2] = fmaf(hv, wv.z, o[jq * 4 + 2]);
            o[jq * 4 + 3] = fmaf(hv, wv.w, o[jq * 4 + 3]);
        }
    }

    if (valid) {
        float4* o4 = reinterpret_cast<float4*>(out + (size_t)n * ND);
        #pragma unroll
        for (int i = 0; i < ND / 4; ++i)
            o4[i] = make_float4(o[4 * i + 0], o[4 * i + 1], o[4 * i + 2], o[4 * i + 3]);
    }
}

extern "C" void kernel_launch(void* const* d_in, const int* in_sizes, int n_in,
                              void* d_out, int out_size, void* d_ws, size_t ws_size,
                              hipStream_t stream)
{
    const float* nf  = (const float*)d_in[0];
    const float* ef  = (const float*)d_in[1];
    const float* w1  = (const float*)d_in[2];
    const float* b1  = (const float*)d_in[3];
    const float* w2  = (const float*)d_in[4];
    const float* b2  = (const float*)d_in[5];
    const float* uw1 = (const float*)d_in[6];
    const float* ub1 = (const float*)d_in[7];
    const float* uw2 = (const float*)d_in[8];
    const float* ub2 = (const float*)d_in[9];
    const int*   src = (const int*)d_in[10];
    const int*   dst = (const int*)d_in[11];
    float* out = (float*)d_out;

    float* agg = (float*)d_ws;                    // [NN][HID]
    float* deg = agg + (size_t)NN * HID;          // [NN]
    hipMemsetAsync(d_ws, 0, ((size_t)NN * HID + NN) * sizeof(float), stream);

    edge_msg_kernel<<<NE / TILE, TILE, 0, stream>>>(nf, ef, w1, b1, w2, b2,
                                                    src, dst, agg, deg);
    node_update_kernel<<<(NN + 255) / 256, 256, 0, stream>>>(nf, agg, deg,
                                                             uw1, ub1, uw2, ub2, out);
}

// Round 3
// 388.138 us; speedup vs baseline: 7.6758x; 2.2655x over previous
//
#include <hip/hip_runtime.h>

#define NN 50000
#define NE 800000
#define ND 64
#define ED 32
#define HID 64
#define NL 2
#define IN_MSG 96   // ND + ED
#define IN_UPD 128  // ND + HID

#define EPB 128     // edges per block (4 waves x 32 edges)
#define CMB_LD 104  // padded bf16 stride for combined (96+8) -> 208 B rows
#define H_LD 72     // padded bf16 stride for h (64+8)        -> 144 B rows
#define MSG_LD 68   // padded f32 stride for msg staging (64+4)

typedef __attribute__((ext_vector_type(8))) short short8;  // 8 bf16 = 4 VGPR
typedef __attribute__((ext_vector_type(4))) float f32x4;

__device__ inline ushort bf16r(float f) {  // fp32 -> bf16 bits, RNE
    union { float f; unsigned u; } x; x.f = f;
    return (ushort)((x.u + 0x7FFFu + ((x.u >> 16) & 1u)) >> 16);
}

// ---------------------------------------------------------------------------
// Edge message MLP via bf16 MFMA. Per block: 128 edges. Per wave: 32 edges
// x 64 outputs = 2x4 tiles of 16x16. fp32 accumulation; weights staged
// transposed in LDS so B-frags are contiguous ds_read_b128. Scatter via the
// proven LDS-transpose + coalesced 64-lane row atomics.
// ---------------------------------------------------------------------------
__global__ __launch_bounds__(256, 2)
void edge_msg_kernel(const float* __restrict__ nf,
                     const float* __restrict__ ef,
                     const float* __restrict__ w1,
                     const float* __restrict__ b1,
                     const float* __restrict__ w2,
                     const float* __restrict__ b2,
                     const int* __restrict__ src,
                     const int* __restrict__ dst,
                     float* __restrict__ agg,
                     float* __restrict__ deg)
{
    // cmb/h region, overlaid by the msg staging buffer after compute
    __shared__ __align__(16) unsigned char smemA[EPB * CMB_LD * 2 + EPB * H_LD * 2]; // 45,056 B
    __shared__ __align__(16) ushort sW1t[64][CMB_LD];  // W1^T bf16, 13,312 B
    __shared__ __align__(16) ushort sW2t[64][H_LD];    // W2^T bf16,  9,216 B
    __shared__ float sB1[64];

    ushort (*sCmb)[CMB_LD] = reinterpret_cast<ushort(*)[CMB_LD]>(smemA);
    ushort (*sH)[H_LD]     = reinterpret_cast<ushort(*)[H_LD]>(smemA + EPB * CMB_LD * 2);
    float  (*sMsg)[MSG_LD] = reinterpret_cast<float(*)[MSG_LD]>(smemA);

    const int tid = threadIdx.x;
    const int w   = tid >> 6;
    const int l   = tid & 63;
    const int lr  = l & 15;
    const int lg  = l >> 4;
    const int e0  = blockIdx.x * EPB;

    // ---- stage combined features (wave-private 32 edge rows), fp32->bf16 ----
    #pragma unroll
    for (int it = 0; it < 8; ++it) {            // node feats: 16 lanes/row
        const int eL = w * 32 + lg + 4 * it;
        const int s  = src[e0 + eL];
        const float4 v = reinterpret_cast<const float4*>(nf + (size_t)s * ND)[lr];
        const unsigned lo = (unsigned)bf16r(v.x) | ((unsigned)bf16r(v.y) << 16);
        const unsigned hi = (unsigned)bf16r(v.z) | ((unsigned)bf16r(v.w) << 16);
        *reinterpret_cast<uint2*>(&sCmb[eL][lr * 4]) = make_uint2(lo, hi);
    }
    #pragma unroll
    for (int it = 0; it < 4; ++it) {            // edge feats: 8 lanes/row
        const int eL = w * 32 + (l >> 3) + 8 * it;
        const int q  = l & 7;
        const float4 v = reinterpret_cast<const float4*>(ef + (size_t)(e0 + eL) * ED)[q];
        const unsigned lo = (unsigned)bf16r(v.x) | ((unsigned)bf16r(v.y) << 16);
        const unsigned hi = (unsigned)bf16r(v.z) | ((unsigned)bf16r(v.w) << 16);
        *reinterpret_cast<uint2*>(&sCmb[eL][ND + q * 4]) = make_uint2(lo, hi);
    }

    // ---- msg accumulators (persist across both layers), init = b2[0]+b2[1] ----
    f32x4 msg[2][4];
    #pragma unroll
    for (int nt = 0; nt < 4; ++nt) {
        const int col = nt * 16 + lr;
        const float v = b2[col] + b2[HID + col];
        #pragma unroll
        for (int mt = 0; mt < 2; ++mt) msg[mt][nt] = (f32x4){v, v, v, v};
    }

    #pragma unroll
    for (int lay = 0; lay < NL; ++lay) {
        __syncthreads();
        // ---- cooperative transpose-stage of this layer's weights ----
        {
            const int k16 = tid >> 4, n0 = (tid & 15) * 4;
            #pragma unroll
            for (int it = 0; it < 6; ++it) {
                const int k = k16 + 16 * it;   // 0..95
                const float4 v = *reinterpret_cast<const float4*>(
                    w1 + ((size_t)lay * IN_MSG + k) * HID + n0);
                sW1t[n0 + 0][k] = bf16r(v.x);
                sW1t[n0 + 1][k] = bf16r(v.y);
                sW1t[n0 + 2][k] = bf16r(v.z);
                sW1t[n0 + 3][k] = bf16r(v.w);
            }
            #pragma unroll
            for (int it = 0; it < 4; ++it) {
                const int k = k16 + 16 * it;   // 0..63
                const float4 v = *reinterpret_cast<const float4*>(
                    w2 + ((size_t)lay * HID + k) * HID + n0);
                sW2t[n0 + 0][k] = bf16r(v.x);
                sW2t[n0 + 1][k] = bf16r(v.y);
                sW2t[n0 + 2][k] = bf16r(v.z);
                sW2t[n0 + 3][k] = bf16r(v.w);
            }
            if (tid < 64) sB1[tid] = b1[lay * HID + tid];
        }
        __syncthreads();

        // ---- GEMM1: h = relu(cmb @ W1 + b1), K=96 ----
        #pragma unroll
        for (int mt = 0; mt < 2; ++mt) {
            const int rA = w * 32 + mt * 16 + lr;
            const short8 A0 = *reinterpret_cast<const short8*>(&sCmb[rA][ 0 + 8 * lg]);
            const short8 A1 = *reinterpret_cast<const short8*>(&sCmb[rA][32 + 8 * lg]);
            const short8 A2 = *reinterpret_cast<const short8*>(&sCmb[rA][64 + 8 * lg]);
            #pragma unroll
            for (int nt = 0; nt < 4; ++nt) {
                const int cB = nt * 16 + lr;
                const short8 B0 = *reinterpret_cast<const short8*>(&sW1t[cB][ 0 + 8 * lg]);
                const short8 B1 = *reinterpret_cast<const short8*>(&sW1t[cB][32 + 8 * lg]);
                const short8 B2 = *reinterpret_cast<const short8*>(&sW1t[cB][64 + 8 * lg]);
                const float bv = sB1[cB];
                f32x4 acc = (f32x4){bv, bv, bv, bv};
                acc = __builtin_amdgcn_mfma_f32_16x16x32_bf16(A0, B0, acc, 0, 0, 0);
                acc = __builtin_amdgcn_mfma_f32_16x16x32_bf16(A1, B1, acc, 0, 0, 0);
                acc = __builtin_amdgcn_mfma_f32_16x16x32_bf16(A2, B2, acc, 0, 0, 0);
                // C layout (m89): col = lane&15, row = (lane>>4)*4 + reg
                const int rH = w * 32 + mt * 16 + 4 * lg;
                #pragma unroll
                for (int r = 0; r < 4; ++r)
                    sH[rH + r][cB] = bf16r(fmaxf(acc[r], 0.0f));
            }
        }

        // ---- GEMM2: msg += h @ W2, K=64 (intra-wave h reuse; no barrier) ----
        #pragma unroll
        for (int mt = 0; mt < 2; ++mt) {
            const int rA = w * 32 + mt * 16 + lr;
            const short8 A0 = *reinterpret_cast<const short8*>(&sH[rA][ 0 + 8 * lg]);
            const short8 A1 = *reinterpret_cast<const short8*>(&sH[rA][32 + 8 * lg]);
            #pragma unroll
            for (int nt = 0; nt < 4; ++nt) {
                const int cB = nt * 16 + lr;
                const short8 B0 = *reinterpret_cast<const short8*>(&sW2t[cB][ 0 + 8 * lg]);
                const short8 B1 = *reinterpret_cast<const short8*>(&sW2t[cB][32 + 8 * lg]);
                msg[mt][nt] = __builtin_amdgcn_mfma_f32_16x16x32_bf16(A0, B0, msg[mt][nt], 0, 0, 0);
                msg[mt][nt] = __builtin_amdgcn_mfma_f32_16x16x32_bf16(A1, B1, msg[mt][nt], 0, 0, 0);
            }
        }
    }

    // ---- stage msg into LDS (overlays cmb/h -> barrier), then flush ----
    __syncthreads();
    #pragma unroll
    for (int mt = 0; mt < 2; ++mt)
        #pragma unroll
        for (int nt = 0; nt < 4; ++nt) {
            const int rM = w * 32 + mt * 16 + 4 * lg;
            #pragma unroll
            for (int r = 0; r < 4; ++r)
                sMsg[rM + r][nt * 16 + lr] = msg[mt][nt][r];
        }
    __syncthreads();

    #pragma unroll 4
    for (int r = 0; r < 32; ++r) {
        const int eL = w * 32 + r;
        const int d  = dst[e0 + eL];
        const float v = sMsg[eL][l];
        atomicAdd(&agg[(size_t)d * HID + l], v);
        if (l == 0) atomicAdd(&deg[d], 1.0f);
    }
}

// ---------------------------------------------------------------------------
// Kernel 2: per-node update MLP (unchanged fp32 LDS-weight version).
// ---------------------------------------------------------------------------
__global__ __launch_bounds__(256, 3)
void node_update_kernel(const float* __restrict__ nf,
                        const float* __restrict__ agg,
                        const float* __restrict__ deg,
                        const float* __restrict__ uw1,
                        const float* __restrict__ ub1,
                        const float* __restrict__ uw2,
                        const float* __restrict__ ub2,
                        float* __restrict__ out)
{
    __shared__ float sW1[IN_UPD * HID];   // 32 KB
    __shared__ float sW2[HID * ND];       // 16 KB

    const int tid = threadIdx.x;
    {
        const float4* g1 = reinterpret_cast<const float4*>(uw1);
        float4* s1 = reinterpret_cast<float4*>(sW1);
        #pragma unroll
        for (int i = 0; i < 8; ++i) s1[tid + 256 * i] = g1[tid + 256 * i];
        const float4* g2 = reinterpret_cast<const float4*>(uw2);
        float4* s2 = reinterpret_cast<float4*>(sW2);
        #pragma unroll
        for (int i = 0; i < 4; ++i) s2[tid + 256 * i] = g2[tid + 256 * i];
    }
    __syncthreads();

    const int n = blockIdx.x * 256 + tid;
    const bool valid = (n < NN);
    const int nc = valid ? n : (NN - 1);

    const float invd = 1.0f / (deg[nc] + 1e-8f);
    const float4* nf4 = reinterpret_cast<const float4*>(nf + (size_t)nc * ND);
    const float4* ag4 = reinterpret_cast<const float4*>(agg + (size_t)nc * HID);

    float h[HID];
    #pragma unroll
    for (int j = 0; j < HID; ++j) h[j] = ub1[j];

    #pragma unroll 1
    for (int kc = 0; kc < ND; kc += 8) {
        const float4 va = nf4[(kc >> 2) + 0];
        const float4 vb = nf4[(kc >> 2) + 1];
        const float c[8] = {va.x, va.y, va.z, va.w, vb.x, vb.y, vb.z, vb.w};
        #pragma unroll
        for (int i = 0; i < 8; ++i) {
            const float* row = sW1 + (kc + i) * HID;
            #pragma unroll
            for (int jq = 0; jq < 16; ++jq) {
                const float4 wv = *reinterpret_cast<const float4*>(row + jq * 4);
                h[jq * 4 + 0] = fmaf(c[i], wv.x, h[jq * 4 + 0]);
                h[jq * 4 + 1] = fmaf(c[i], wv.y, h[jq * 4 + 1]);
                h[jq * 4 + 2] = fmaf(c[i], wv.z, h[jq * 4 + 2]);
                h[jq * 4 + 3] = fmaf(c[i], wv.w, h[jq * 4 + 3]);
            }
        }
    }
    #pragma unroll 1
    for (int kc = 0; kc < HID; kc += 8) {
        const float4 va = ag4[(kc >> 2) + 0];
        const float4 vb = ag4[(kc >> 2) + 1];
        const float c[8] = {va.x * invd, va.y * invd, va.z * invd, va.w * invd,
                            vb.x * invd, vb.y * invd, vb.z * invd, vb.w * invd};
        #pragma unroll
        for (int i = 0; i < 8; ++i) {
            const float* row = sW1 + (ND + kc + i) * HID;
            #pragma unroll
            for (int jq = 0; jq < 16; ++jq) {
                const float4 wv = *reinterpret_cast<const float4*>(row + jq * 4);
                h[jq * 4 + 0] = fmaf(c[i], wv.x, h[jq * 4 + 0]);
                h[jq * 4 + 1] = fmaf(c[i], wv.y, h[jq * 4 + 1]);
                h[jq * 4 + 2] = fmaf(c[i], wv.z, h[jq * 4 + 2]);
                h[jq * 4 + 3] = fmaf(c[i], wv.w, h[jq * 4 + 3]);
            }
        }
    }
    #pragma unroll
    for (int j = 0; j < HID; ++j) h[j] = fmaxf(h[j], 0.0f);

    float o[ND];
    #pragma unroll
    for (int j = 0; j < ND; ++j) o[j] = ub2[j];

    #pragma unroll
    for (int k = 0; k < HID; ++k) {
        const float hv = h[k];
        const float* row = sW2 + k * ND;
        #pragma unroll
        for (int jq = 0; jq < 16; ++jq) {
            const float4 wv = *reinterpret_cast<const float4*>(row + jq * 4);
            o[jq * 4 + 0] = fmaf(hv, wv.x, o[jq * 4 + 0]);
            o[jq * 4 + 1] = fmaf(hv, wv.y, o[jq * 4 + 1]);
            o[jq * 4 + 2] = fmaf(hv, wv.z, o[jq * 4 + 2]);
            o[jq * 4 + 3] = fmaf(hv, wv.w, o[jq * 4 + 3]);
        }
    }

    if (valid) {
        float4* o4 = reinterpret_cast<float4*>(out + (size_t)n * ND);
        #pragma unroll
        for (int i = 0; i < ND / 4; ++i)
            o4[i] = make_float4(o[4 * i + 0], o[4 * i + 1], o[4 * i + 2], o[4 * i + 3]);
    }
}

extern "C" void kernel_launch(void* const* d_in, const int* in_sizes, int n_in,
                              void* d_out, int out_size, void* d_ws, size_t ws_size,
                              hipStream_t stream)
{
    const float* nf  = (const float*)d_in[0];
    const float* ef  = (const float*)d_in[1];
    const float* w1  = (const float*)d_in[2];
    const float* b1  = (const float*)d_in[3];
    const float* w2  = (const float*)d_in[4];
    const float* b2  = (const float*)d_in[5];
    const float* uw1 = (const float*)d_in[6];
    const float* ub1 = (const float*)d_in[7];
    const float* uw2 = (const float*)d_in[8];
    const float* ub2 = (const float*)d_in[9];
    const int*   src = (const int*)d_in[10];
    const int*   dst = (const int*)d_in[11];
    float* out = (float*)d_out;

    float* agg = (float*)d_ws;                    // [NN][HID]
    float* deg = agg + (size_t)NN * HID;          // [NN]
    hipMemsetAsync(d_ws, 0, ((size_t)NN * HID + NN) * sizeof(float), stream);

    edge_msg_kernel<<<NE / EPB, 256, 0, stream>>>(nf, ef, w1, b1, w2, b2,
                                                  src, dst, agg, deg);
    node_update_kernel<<<(NN + 255) / 256, 256, 0, stream>>>(nf, agg, deg,
                                                             uw1, ub1, uw2, ub2, out);
}

// Round 4
// 239.897 us; speedup vs baseline: 12.4190x; 1.6179x over previous
//
#include <hip/hip_runtime.h>

#define NN 50000
#define NE 800000
#define ND 64
#define ED 32
#define HID 64
#define NL 2
#define IN_MSG 96   // ND + ED
#define IN_UPD 128  // ND + HID

#define CMB_LD 104  // ushort stride for combined rows (96+8)
#define H_LD 72     // ushort stride for h rows (64+8)
#define UPD_LD 136  // ushort stride for node comb rows (128+8)

#define NBLK 512
#define WPB 4
#define TOTW (NBLK * WPB)   // 2048 waves
#define NGRP (NE / 32)      // 25000 groups of 32 edges

typedef __attribute__((ext_vector_type(8))) short short8;  // 8 bf16 = 4 VGPR
typedef __attribute__((ext_vector_type(4))) float f32x4;

__device__ inline ushort bf16r(float f) {  // fp32 -> bf16, RNE
    union { float f; unsigned u; } x; x.f = f;
    return (ushort)((x.u + 0x7FFFu + ((x.u >> 16) & 1u)) >> 16);
}
__device__ inline uint2 pack4(float4 v) {
    return make_uint2((unsigned)bf16r(v.x) | ((unsigned)bf16r(v.y) << 16),
                      (unsigned)bf16r(v.z) | ((unsigned)bf16r(v.w) << 16));
}

// ---------------------------------------------------------------------------
// Edge message MLP: persistent waves, barrier-free main loop.
// Per wave-group: 32 edges x 64 outputs (2 mt x 4 nt tiles, 16x16x32 bf16).
// W1 in LDS (staged once/block), W2 fragments in registers, features
// software-pipelined one group ahead. Scatter = direct C-frag atomics.
// ---------------------------------------------------------------------------
__global__ __launch_bounds__(256, 2)
void edge_msg_kernel(const float* __restrict__ nf,
                     const float* __restrict__ ef,
                     const float* __restrict__ w1,
                     const float* __restrict__ b1,
                     const float* __restrict__ w2,
                     const float* __restrict__ b2,
                     const int* __restrict__ src,
                     const int* __restrict__ dst,
                     float* __restrict__ agg,
                     float* __restrict__ deg)
{
    __shared__ __align__(16) ushort sAct[WPB][32][CMB_LD];   // 26,624 B (wave-private rows)
    __shared__ __align__(16) ushort sH[WPB][32][H_LD];       // 18,432 B (wave-private rows)
    __shared__ __align__(16) ushort sW1t[NL][64][CMB_LD];    // 26,624 B (read-only after stage)
    __shared__ float sB1[NL][64];
    __shared__ float sB2s[64];

    const int tid = threadIdx.x;
    const int w  = tid >> 6;
    const int l  = tid & 63;
    const int lr = l & 15;
    const int lg = l >> 4;

    // ---- one-time stage: W1^T (both layers) + biases ----
    {
        const int k16 = tid >> 4, n0 = (tid & 15) * 4;
        #pragma unroll
        for (int lay = 0; lay < NL; ++lay)
            #pragma unroll
            for (int it = 0; it < 6; ++it) {
                const int k = k16 + 16 * it;   // 0..95
                const float4 v = *reinterpret_cast<const float4*>(
                    w1 + ((size_t)lay * IN_MSG + k) * HID + n0);
                sW1t[lay][n0 + 0][k] = bf16r(v.x);
                sW1t[lay][n0 + 1][k] = bf16r(v.y);
                sW1t[lay][n0 + 2][k] = bf16r(v.z);
                sW1t[lay][n0 + 3][k] = bf16r(v.w);
            }
        if (tid < 64) {
            sB1[0][tid] = b1[tid];
            sB1[1][tid] = b1[HID + tid];
            sB2s[tid]   = b2[tid] + b2[HID + tid];
        }
    }

    // ---- one-time: W2 B-fragments into registers (both layers) ----
    short8 w2f[NL][4][2];
    #pragma unroll
    for (int lay = 0; lay < NL; ++lay)
        #pragma unroll
        for (int nt = 0; nt < 4; ++nt)
            #pragma unroll
            for (int ks = 0; ks < 2; ++ks) {
                short8 t;
                #pragma unroll
                for (int j = 0; j < 8; ++j)
                    t[j] = (short)bf16r(
                        w2[((size_t)lay * HID + ks * 32 + 8 * lg + j) * HID + nt * 16 + lr]);
                w2f[lay][nt][ks] = t;
            }
    __syncthreads();   // the only block-wide barrier

    // ---- persistent grid-stride loop over 32-edge groups ----
    int g = blockIdx.x * WPB + w;            // 0..2047 < NGRP
    int srcv = 0, dstv = 0;
    if (l < 32) { srcv = src[(size_t)g * 32 + l]; dstv = dst[(size_t)g * 32 + l]; }
    float4 nfv[8], efv[4];
    #pragma unroll
    for (int it = 0; it < 8; ++it) {
        const int s = __shfl(srcv, lg + 4 * it);
        nfv[it] = reinterpret_cast<const float4*>(nf + (size_t)s * ND)[lr];
    }
    #pragma unroll
    for (int it = 0; it < 4; ++it)
        efv[it] = reinterpret_cast<const float4*>(ef + (size_t)(g * 32 + (l >> 3) + 8 * it) * ED)[l & 7];

    while (g < NGRP) {
        const int gn   = g + TOTW;
        const bool more = (gn < NGRP);

        // stage current group's features (own LDS rows; no barrier needed)
        #pragma unroll
        for (int it = 0; it < 8; ++it) {
            const int row = lg + 4 * it;
            *reinterpret_cast<uint2*>(&sAct[w][row][lr * 4]) = pack4(nfv[it]);
        }
        #pragma unroll
        for (int it = 0; it < 4; ++it) {
            const int row = (l >> 3) + 8 * it;
            *reinterpret_cast<uint2*>(&sAct[w][row][ND + (l & 7) * 4]) = pack4(efv[it]);
        }

        // prefetch next group's indices
        int srcn = 0, dstn = 0;
        if (more && l < 32) {
            srcn = src[(size_t)gn * 32 + l];
            dstn = dst[(size_t)gn * 32 + l];
        }

        f32x4 msg[2][4];
        #pragma unroll
        for (int nt = 0; nt < 4; ++nt) {
            const float v = sB2s[nt * 16 + lr];
            msg[0][nt] = (f32x4){v, v, v, v};
            msg[1][nt] = (f32x4){v, v, v, v};
        }

        #pragma unroll
        for (int lay = 0; lay < NL; ++lay) {
            // ---- GEMM1: h = relu(cmb @ W1 + b1), K=96 ----
            short8 A[2][3];
            #pragma unroll
            for (int mt = 0; mt < 2; ++mt)
                #pragma unroll
                for (int ks = 0; ks < 3; ++ks)
                    A[mt][ks] = *reinterpret_cast<const short8*>(
                        &sAct[w][mt * 16 + lr][ks * 32 + 8 * lg]);
            #pragma unroll
            for (int nt = 0; nt < 4; ++nt) {
                const int cB = nt * 16 + lr;
                const short8 B0 = *reinterpret_cast<const short8*>(&sW1t[lay][cB][ 0 + 8 * lg]);
                const short8 B1 = *reinterpret_cast<const short8*>(&sW1t[lay][cB][32 + 8 * lg]);
                const short8 B2 = *reinterpret_cast<const short8*>(&sW1t[lay][cB][64 + 8 * lg]);
                const float bv = sB1[lay][cB];
                #pragma unroll
                for (int mt = 0; mt < 2; ++mt) {
                    f32x4 acc = (f32x4){bv, bv, bv, bv};
                    acc = __builtin_amdgcn_mfma_f32_16x16x32_bf16(A[mt][0], B0, acc, 0, 0, 0);
                    acc = __builtin_amdgcn_mfma_f32_16x16x32_bf16(A[mt][1], B1, acc, 0, 0, 0);
                    acc = __builtin_amdgcn_mfma_f32_16x16x32_bf16(A[mt][2], B2, acc, 0, 0, 0);
                    const int rH = mt * 16 + 4 * lg;   // C layout: col=lane&15, row=(lane>>4)*4+reg
                    #pragma unroll
                    for (int r = 0; r < 4; ++r)
                        sH[w][rH + r][cB] = bf16r(fmaxf(acc[r], 0.0f));
                }
            }

            // prefetch next group's features under layer-0's remaining compute
            if (lay == 0 && more) {
                #pragma unroll
                for (int it = 0; it < 8; ++it) {
                    const int s = __shfl(srcn, lg + 4 * it);
                    nfv[it] = reinterpret_cast<const float4*>(nf + (size_t)s * ND)[lr];
                }
                #pragma unroll
                for (int it = 0; it < 4; ++it)
                    efv[it] = reinterpret_cast<const float4*>(
                        ef + (size_t)(gn * 32 + (l >> 3) + 8 * it) * ED)[l & 7];
            }

            // ---- GEMM2: msg += h @ W2 (W2 frags in registers), K=64 ----
            #pragma unroll
            for (int mt = 0; mt < 2; ++mt) {
                const short8 A0 = *reinterpret_cast<const short8*>(&sH[w][mt * 16 + lr][ 0 + 8 * lg]);
                const short8 A1 = *reinterpret_cast<const short8*>(&sH[w][mt * 16 + lr][32 + 8 * lg]);
                #pragma unroll
                for (int nt = 0; nt < 4; ++nt) {
                    msg[mt][nt] = __builtin_amdgcn_mfma_f32_16x16x32_bf16(A0, w2f[lay][nt][0], msg[mt][nt], 0, 0, 0);
                    msg[mt][nt] = __builtin_amdgcn_mfma_f32_16x16x32_bf16(A1, w2f[lay][nt][1], msg[mt][nt], 0, 0, 0);
                }
            }
        }

        // ---- flush: direct C-frag atomics (4 rows x 64B contiguous per instr) ----
        int drow[2][4];
        #pragma unroll
        for (int mt = 0; mt < 2; ++mt)
            #pragma unroll
            for (int r = 0; r < 4; ++r)
                drow[mt][r] = __shfl(dstv, mt * 16 + 4 * lg + r);
        #pragma unroll
        for (int mt = 0; mt < 2; ++mt)
            #pragma unroll
            for (int r = 0; r < 4; ++r) {
                float* rowp = agg + (size_t)drow[mt][r] * HID;
                #pragma unroll
                for (int nt = 0; nt < 4; ++nt)
                    atomicAdd(rowp + nt * 16 + lr, msg[mt][nt][r]);
            }
        if (l < 32) atomicAdd(&deg[dstv], 1.0f);

        srcv = srcn; dstv = dstn;
        g = gn;
    }
}

// ---------------------------------------------------------------------------
// Node update MLP via bf16 MFMA: one 32-node group per wave, K=128 then K=64.
// h overlays comb (cols 0..63) after A-fragments are register-resident.
// ---------------------------------------------------------------------------
__global__ __launch_bounds__(256, 2)
void node_update_kernel(const float* __restrict__ nf,
                        const float* __restrict__ agg,
                        const float* __restrict__ deg,
                        const float* __restrict__ uw1,
                        const float* __restrict__ ub1,
                        const float* __restrict__ uw2,
                        const float* __restrict__ ub2,
                        float* __restrict__ out)
{
    __shared__ __align__(16) ushort sAct[WPB][32][UPD_LD];   // 34,816 B
    __shared__ __align__(16) ushort sW1t[64][UPD_LD];        // 17,408 B
    __shared__ __align__(16) ushort sW2t[64][H_LD];          //  9,216 B
    __shared__ float sUB1[64], sUB2[64];

    const int tid = threadIdx.x;
    const int w  = tid >> 6;
    const int l  = tid & 63;
    const int lr = l & 15;
    const int lg = l >> 4;

    {   // weight stage
        const int k16 = tid >> 4, n0 = (tid & 15) * 4;
        #pragma unroll
        for (int it = 0; it < 8; ++it) {
            const int k = k16 + 16 * it;    // 0..127
            const float4 v = *reinterpret_cast<const float4*>(uw1 + (size_t)k * HID + n0);
            sW1t[n0 + 0][k] = bf16r(v.x);
            sW1t[n0 + 1][k] = bf16r(v.y);
            sW1t[n0 + 2][k] = bf16r(v.z);
            sW1t[n0 + 3][k] = bf16r(v.w);
        }
        #pragma unroll
        for (int it = 0; it < 4; ++it) {
            const int k = k16 + 16 * it;    // 0..63
            const float4 v = *reinterpret_cast<const float4*>(uw2 + (size_t)k * ND + n0);
            sW2t[n0 + 0][k] = bf16r(v.x);
            sW2t[n0 + 1][k] = bf16r(v.y);
            sW2t[n0 + 2][k] = bf16r(v.z);
            sW2t[n0 + 3][k] = bf16r(v.w);
        }
        if (tid < 64) { sUB1[tid] = ub1[tid]; sUB2[tid] = ub2[tid]; }
    }

    const int nbase = blockIdx.x * 128 + w * 32;

    float invv = 0.0f;
    if (l < 32) invv = 1.0f / (deg[min(nbase + l, NN - 1)] + 1e-8f);

    // stage comb2 = [nf | agg/deg] as bf16
    #pragma unroll
    for (int it = 0; it < 8; ++it) {
        const int row = lg + 4 * it;
        const int n = min(nbase + row, NN - 1);
        const float4 v = reinterpret_cast<const float4*>(nf + (size_t)n * ND)[lr];
        *reinterpret_cast<uint2*>(&sAct[w][row][lr * 4]) = pack4(v);
    }
    #pragma unroll
    for (int it = 0; it < 8; ++it) {
        const int row = lg + 4 * it;
        const int n = min(nbase + row, NN - 1);
        const float iv = __shfl(invv, row);
        float4 v = reinterpret_cast<const float4*>(agg + (size_t)n * HID)[lr];
        v.x *= iv; v.y *= iv; v.z *= iv; v.w *= iv;
        *reinterpret_cast<uint2*>(&sAct[w][row][ND + lr * 4]) = pack4(v);
    }
    __syncthreads();

    // GEMM1: K=128
    short8 A[2][4];
    #pragma unroll
    for (int mt = 0; mt < 2; ++mt)
        #pragma unroll
        for (int ks = 0; ks < 4; ++ks)
            A[mt][ks] = *reinterpret_cast<const short8*>(&sAct[w][mt * 16 + lr][ks * 32 + 8 * lg]);
    #pragma unroll
    for (int nt = 0; nt < 4; ++nt) {
        const int cB = nt * 16 + lr;
        short8 B[4];
        #pragma unroll
        for (int ks = 0; ks < 4; ++ks)
            B[ks] = *reinterpret_cast<const short8*>(&sW1t[cB][ks * 32 + 8 * lg]);
        const float bv = sUB1[cB];
        #pragma unroll
        for (int mt = 0; mt < 2; ++mt) {
            f32x4 acc = (f32x4){bv, bv, bv, bv};
            #pragma unroll
            for (int ks = 0; ks < 4; ++ks)
                acc = __builtin_amdgcn_mfma_f32_16x16x32_bf16(A[mt][ks], B[ks], acc, 0, 0, 0);
            const int rH = mt * 16 + 4 * lg;
            #pragma unroll
            for (int r = 0; r < 4; ++r)
                sAct[w][rH + r][cB] = bf16r(fmaxf(acc[r], 0.0f));   // h overlays comb cols 0..63
        }
    }

    // GEMM2: out = h @ W2 + ub2, K=64
    f32x4 o[2][4];
    #pragma unroll
    for (int nt = 0; nt < 4; ++nt) {
        const float v = sUB2[nt * 16 + lr];
        o[0][nt] = (f32x4){v, v, v, v};
        o[1][nt] = (f32x4){v, v, v, v};
    }
    #pragma unroll
    for (int mt = 0; mt < 2; ++mt) {
        const short8 A0 = *reinterpret_cast<const short8*>(&sAct[w][mt * 16 + lr][ 0 + 8 * lg]);
        const short8 A1 = *reinterpret_cast<const short8*>(&sAct[w][mt * 16 + lr][32 + 8 * lg]);
        #pragma unroll
        for (int nt = 0; nt < 4; ++nt) {
            const int cB = nt * 16 + lr;
            const short8 B0 = *reinterpret_cast<const short8*>(&sW2t[cB][ 0 + 8 * lg]);
            const short8 B1 = *reinterpret_cast<const short8*>(&sW2t[cB][32 + 8 * lg]);
            o[mt][nt] = __builtin_amdgcn_mfma_f32_16x16x32_bf16(A0, B0, o[mt][nt], 0, 0, 0);
            o[mt][nt] = __builtin_amdgcn_mfma_f32_16x16x32_bf16(A1, B1, o[mt][nt], 0, 0, 0);
        }
    }

    // store (4 rows x 64B contiguous per instruction)
    #pragma unroll
    for (int mt = 0; mt < 2; ++mt)
        #pragma unroll
        for (int r = 0; r < 4; ++r) {
            const int n = nbase + mt * 16 + 4 * lg + r;
            if (n < NN) {
                float* rowp = out + (size_t)n * ND;
                #pragma unroll
                for (int nt = 0; nt < 4; ++nt)
                    rowp[nt * 16 + lr] = o[mt][nt][r];
            }
        }
}

extern "C" void kernel_launch(void* const* d_in, const int* in_sizes, int n_in,
                              void* d_out, int out_size, void* d_ws, size_t ws_size,
                              hipStream_t stream)
{
    const float* nf  = (const float*)d_in[0];
    const float* ef  = (const float*)d_in[1];
    const float* w1  = (const float*)d_in[2];
    const float* b1  = (const float*)d_in[3];
    const float* w2  = (const float*)d_in[4];
    const float* b2  = (const float*)d_in[5];
    const float* uw1 = (const float*)d_in[6];
    const float* ub1 = (const float*)d_in[7];
    const float* uw2 = (const float*)d_in[8];
    const float* ub2 = (const float*)d_in[9];
    const int*   src = (const int*)d_in[10];
    const int*   dst = (const int*)d_in[11];
    float* out = (float*)d_out;

    float* agg = (float*)d_ws;                    // [NN][HID]
    float* deg = agg + (size_t)NN * HID;          // [NN]
    hipMemsetAsync(d_ws, 0, ((size_t)NN * HID + NN) * sizeof(float), stream);

    edge_msg_kernel<<<NBLK, 256, 0, stream>>>(nf, ef, w1, b1, w2, b2,
                                              src, dst, agg, deg);
    node_update_kernel<<<(NN + 127) / 128, 256, 0, stream>>>(nf, agg, deg,
                                                             uw1, ub1, uw2, ub2, out);
}